// Round 4
// baseline (406.590 us; speedup 1.0000x reference)
//
#include <hip/hip_runtime.h>
#include <hip/hip_bf16.h>

typedef short s16x8 __attribute__((ext_vector_type(8)));      // 8 bf16 (4 VGPRs)
typedef float f32x16 __attribute__((ext_vector_type(16)));
typedef unsigned short us8 __attribute__((ext_vector_type(8)));

#define HE   1024
#define SEQ  4096
#define NBAT 32
#define BM   64      // rows per block
#define BKG  64      // k per group (one barrier per group)
#define NG   16      // HE / BKG

__device__ __forceinline__ unsigned short f2bf(float f) {
    unsigned u = __builtin_bit_cast(unsigned, f);
    u += 0x7FFFu + ((u >> 16) & 1u);
    return (unsigned short)(u >> 16);
}

__device__ __forceinline__ float tanh_fast(float x) {
    float e = __expf(2.0f * x);
    return 1.0f - 2.0f / (e + 1.0f);
}

// barrier WITHOUT vmcnt drain: only LDS ops must be cross-wave visible;
// register-destined global loads stay in flight across it.
#define WG_SYNC() do {                                         \
    asm volatile("s_waitcnt lgkmcnt(0)" ::: "memory");         \
    __builtin_amdgcn_s_barrier();                              \
} while (0)

// ---- h_proj partials
__global__ void k_hproj(const float* __restrict__ hidden, const float* __restrict__ W,
                        float* __restrict__ cpart) {
    int b = blockIdx.x >> 3, kc = blockIdx.x & 7;
    int h = threadIdx.x;
    const float* hv = hidden + (NBAT + b) * HE;   // hidden[-1]
    int k0 = kc * 128;
    float acc = 0.f;
    for (int j = 0; j < 128; ++j)
        acc = fmaf(hv[k0 + j], W[(k0 + j) * HE + h], acc);
    cpart[(b * 8 + kc) * HE + h] = acc;
}

__global__ void k_cfinal(const float* __restrict__ cpart, const float* __restrict__ b_attn,
                         float* __restrict__ c) {
    int b = blockIdx.x, h = threadIdx.x;
    float s = b_attn[h];
    #pragma unroll
    for (int kc = 0; kc < 8; ++kc) s += cpart[(b * 8 + kc) * HE + h];
    c[b * HE + h] = s;
}

// ---- pack W_e (= W_attn[He:]) into 32x32x16 MFMA B-fragment order:
// Wp[((kb2*32 + cf)*64 + l)*8 + i] = bf16( W_e[kb2*16 + (l>>5)*8 + i][cf*32 + (l&31)] )
__global__ void k_pack(const float* __restrict__ W, unsigned short* __restrict__ Wp) {
    int gid = blockIdx.x * blockDim.x + threadIdx.x;   // 131072 threads
    int l = gid & 63, cf = (gid >> 6) & 31, kb2 = gid >> 11;
    int krow = HE + kb2 * 16 + ((l >> 5) * 8);
    int col  = cf * 32 + (l & 31);
    us8 v;
    #pragma unroll
    for (int i = 0; i < 8; ++i) v[i] = f2bf(W[(krow + i) * HE + col]);
    *(us8*)(Wp + (long)gid * 8) = v;
}

// ---- main fused kernel: 64 rows x 512 cols per block (col-half), 256 threads,
//      2 blocks/CU for barrier-decorrelated TLP
__global__ __launch_bounds__(256, 2) void k_main(
    const float* __restrict__ E, const us8* __restrict__ Wp,
    const float* __restrict__ C, const float* __restrict__ VW,
    float* __restrict__ spart)
{
    __shared__ unsigned short Abuf[2][BM * BKG];   // 2 x 8 KB, swizzled bf16 E tile
    __shared__ float smred[BM][4];

    const int tid  = threadIdx.x;
    const int lane = tid & 63;
    const int wv   = tid >> 6;           // wave 0..3
    // chunked XCD swizzle: pair-blocks (same stripe) land on same XCD, adjacent in time
    const int wgid = blockIdx.x;
    const int idx  = (wgid & 7) * 512 + (wgid >> 3);   // 4096 blocks, bijective
    const int stripe = idx >> 1;
    const int half   = idx & 1;          // col half 0/1
    const int m0   = stripe * BM;
    const int bb   = m0 >> 12;

    // staging: 256 threads x 16 floats = 64 rows x 64 k per group
    const int s_row = tid >> 2;
    const int s_kq  = tid & 3;           // 16-float chunk within row
    const float* gE = E + (long)(m0 + s_row) * HE + s_kq * 16;
    const int s_sw  = s_row & 7;         // swizzle: 16B-unit ^= row&7 (8 units/row)
    const int s_w0  = s_row * 128 + (((s_kq * 2)     ^ s_sw) << 4);
    const int s_w1  = s_row * 128 + (((s_kq * 2 + 1) ^ s_sw) << 4);

    // A-frag read map: row = rf*32 + (lane&31), k = kb2loc*16 + (lane>>5)*8 + i
    const int l31 = lane & 31, lh = lane >> 5;
    const int a_sw = l31 & 7;            // row&7 (same for rf=0,1)
    const int a_b0 = l31 * 128;
    const int a_b1 = (32 + l31) * 128;

    const int cfb = half * 16 + wv * 4;  // this wave's first col-frag (of 32)
    const us8* WpW = Wp + ((long)cfb * 64 + lane);

    f32x16 acc[2][4];
    #pragma unroll
    for (int rf = 0; rf < 2; ++rf)
        #pragma unroll
        for (int cfi = 0; cfi < 4; ++cfi)
            #pragma unroll
            for (int e = 0; e < 16; ++e) acc[rf][cfi][e] = 0.f;

#define LOADB(dst, kb2i)                                                         \
    _Pragma("unroll")                                                            \
    for (int cfi = 0; cfi < 4; ++cfi)                                            \
        dst[cfi] = __builtin_bit_cast(s16x8, WpW[(long)(kb2i) * 2048 + cfi * 64]);

#define AREAD(dst, base, hi) do {                                                \
    dst = __builtin_bit_cast(s16x8, *(const us8*)((const char*)Ab +              \
            (base) + (((((hi) * 2 + lh)) ^ a_sw) << 4)));                        \
} while (0)

#define MFMA8(af, bf) do {                                                       \
    __builtin_amdgcn_s_setprio(1);                                               \
    _Pragma("unroll")                                                            \
    for (int rf = 0; rf < 2; ++rf)                                               \
        _Pragma("unroll")                                                        \
        for (int cfi = 0; cfi < 4; ++cfi)                                        \
            acc[rf][cfi] = __builtin_amdgcn_mfma_f32_32x32x16_bf16(              \
                af[rf], bf[cfi], acc[rf][cfi], 0, 0, 0);                         \
    __builtin_amdgcn_s_setprio(0);                                               \
} while (0)

#define STAGE_WRITE(buf) do {                                                    \
    us8 w0_, w1_;                                                                \
    w0_[0]=f2bf(ev0.x); w0_[1]=f2bf(ev0.y); w0_[2]=f2bf(ev0.z); w0_[3]=f2bf(ev0.w); \
    w0_[4]=f2bf(ev1.x); w0_[5]=f2bf(ev1.y); w0_[6]=f2bf(ev1.z); w0_[7]=f2bf(ev1.w); \
    w1_[0]=f2bf(ev2.x); w1_[1]=f2bf(ev2.y); w1_[2]=f2bf(ev2.z); w1_[3]=f2bf(ev2.w); \
    w1_[4]=f2bf(ev3.x); w1_[5]=f2bf(ev3.y); w1_[6]=f2bf(ev3.z); w1_[7]=f2bf(ev3.w); \
    *(us8*)((char*)&Abuf[buf][0] + s_w0) = w0_;                                  \
    *(us8*)((char*)&Abuf[buf][0] + s_w1) = w1_;                                  \
} while (0)

    s16x8 b0[4], b1[4];
    s16x8 a0[2], a1[2];
    float4 ev0, ev1, ev2, ev3;

    // prologue: stage group 0, preload B for kb2=0
    ev0 = *(const float4*)(gE + 0);
    ev1 = *(const float4*)(gE + 4);
    ev2 = *(const float4*)(gE + 8);
    ev3 = *(const float4*)(gE + 12);
    LOADB(b0, 0);
    STAGE_WRITE(0);
    WG_SYNC();

    for (int g = 0; g < NG; ++g) {
        const int p2 = g & 1;
        const unsigned short* Ab = &Abuf[p2][0];
        const int k4 = g * 4;

        // issue E loads for group g+1 (consumed at group end -> ~4 phases of slack)
        if (g + 1 < NG) {
            const float* gn = gE + (g + 1) * BKG;
            ev0 = *(const float4*)(gn + 0);
            ev1 = *(const float4*)(gn + 4);
            ev2 = *(const float4*)(gn + 8);
            ev3 = *(const float4*)(gn + 12);
        }

        AREAD(a0[0], a_b0, 0);
        AREAD(a0[1], a_b1, 0);

        // phase 0
        LOADB(b1, k4 + 1);
        AREAD(a1[0], a_b0, 1);
        AREAD(a1[1], a_b1, 1);
        MFMA8(a0, b0);
        // phase 1
        LOADB(b0, k4 + 2);
        AREAD(a0[0], a_b0, 2);
        AREAD(a0[1], a_b1, 2);
        MFMA8(a1, b1);
        // phase 2
        LOADB(b1, k4 + 3);
        AREAD(a1[0], a_b0, 3);
        AREAD(a1[1], a_b1, 3);
        MFMA8(a0, b0);
        // phase 3
        {
            int nk = k4 + 4; if (nk > 63) nk = 63;   // clamp at tail
            LOADB(b0, nk);
        }
        if (g + 1 < NG) STAGE_WRITE(1 - p2);
        MFMA8(a1, b1);
        WG_SYNC();
    }

#undef LOADB
#undef AREAD
#undef MFMA8
#undef STAGE_WRITE

    // fused epilogue: partial score over this block's 512 cols
    float cv[4], vv[4];
    #pragma unroll
    for (int cfi = 0; cfi < 4; ++cfi) {
        int col = (cfb + cfi) * 32 + l31;
        cv[cfi] = C[bb * HE + col];
        vv[cfi] = VW[col];
    }
    #pragma unroll
    for (int rf = 0; rf < 2; ++rf) {
        #pragma unroll
        for (int reg = 0; reg < 16; ++reg) {
            float pS = 0.f;
            #pragma unroll
            for (int cfi = 0; cfi < 4; ++cfi)
                pS += tanh_fast(acc[rf][cfi][reg] + cv[cfi]) * vv[cfi];
            pS += __shfl_xor(pS, 1);
            pS += __shfl_xor(pS, 2);
            pS += __shfl_xor(pS, 4);
            pS += __shfl_xor(pS, 8);
            pS += __shfl_xor(pS, 16);
            if (l31 == 0) {
                int row = rf * 32 + (reg & 3) + 8 * (reg >> 2) + 4 * lh;
                smred[row][wv] = pS;
            }
        }
    }
    __syncthreads();
    if (tid < BM) {
        float s = smred[tid][0] + smred[tid][1] + smred[tid][2] + smred[tid][3];
        spart[(long)half * (NBAT * SEQ) + m0 + tid] = s;
    }
}

// ---- softmax over S=4096 per batch row (sums the two col-half partials)
__global__ void k_softmax(const float* __restrict__ spart, float* __restrict__ out) {
    __shared__ float red[16];
    __shared__ float red2[16];
    int b = blockIdx.x, tid = threadIdx.x;
    const float* s0 = spart + (long)b * SEQ;
    const float* s1 = spart + (long)NBAT * SEQ + (long)b * SEQ;
    float v[4];
    float mx = -1e30f;
    #pragma unroll
    for (int j = 0; j < 4; ++j) {
        v[j] = s0[tid + j * 1024] + s1[tid + j * 1024];
        mx = fmaxf(mx, v[j]);
    }
    #pragma unroll
    for (int off = 32; off; off >>= 1) mx = fmaxf(mx, __shfl_xor(mx, off));
    if ((tid & 63) == 0) red[tid >> 6] = mx;
    __syncthreads();
    mx = red[0];
    #pragma unroll
    for (int i = 1; i < 16; ++i) mx = fmaxf(mx, red[i]);
    float sum = 0.f;
    #pragma unroll
    for (int j = 0; j < 4; ++j) { v[j] = expf(v[j] - mx); sum += v[j]; }
    #pragma unroll
    for (int off = 32; off; off >>= 1) sum += __shfl_xor(sum, off);
    if ((tid & 63) == 0) red2[tid >> 6] = sum;
    __syncthreads();
    sum = 0.f;
    #pragma unroll
    for (int i = 0; i < 16; ++i) sum += red2[i];
    float inv = 1.0f / sum;
    #pragma unroll
    for (int j = 0; j < 4; ++j) out[b * SEQ + tid + j * 1024] = v[j] * inv;
}

extern "C" void kernel_launch(void* const* d_in, const int* in_sizes, int n_in,
                              void* d_out, int out_size, void* d_ws, size_t ws_size,
                              hipStream_t stream)
{
    const float* hidden = (const float*)d_in[0];
    const float* enc    = (const float*)d_in[1];
    const float* W      = (const float*)d_in[2];
    const float* b_attn = (const float*)d_in[3];
    const float* v_w    = (const float*)d_in[4];
    float* out          = (float*)d_out;

    char* ws = (char*)d_ws;
    unsigned short* Wp = (unsigned short*)(ws);                        // 2 MB packed bf16 W_e
    float* cpart       = (float*)(ws + (2u << 20));                    // 1 MB
    float* Cc          = (float*)(ws + (3u << 20));                    // 128 KB
    float* spart       = (float*)(ws + (3u << 20) + (128u << 10));     // 2 x 512 KB partial scores

    k_pack   <<<512, 256,  0, stream>>>(W, Wp);
    k_hproj  <<<256, 1024, 0, stream>>>(hidden, W, cpart);
    k_cfinal <<<32,  1024, 0, stream>>>(cpart, b_attn, Cc);
    k_main   <<<4096, 256, 0, stream>>>(enc, (const us8*)Wp, Cc, v_w, spart);
    k_softmax<<<32,  1024, 0, stream>>>(spart, out);
}